// Round 3
// baseline (543.001 us; speedup 1.0000x reference)
//
#include <hip/hip_runtime.h>

#define N_NODES 100000
#define N_EDGES 1600000
#define NBKT 391          // buckets of 256 rows each (391*256 = 100096 >= N)

// ---------------- Pass A: bucket histogram (LDS-reduced) ----------------
__global__ __launch_bounds__(256) void bhist_kernel(const int* __restrict__ row,
                                                    unsigned* __restrict__ bucketcnt, int E) {
    __shared__ unsigned h[NBKT];
    int t = threadIdx.x;
    for (int i = t; i < NBKT; i += 256) h[i] = 0;
    __syncthreads();
    for (int i = blockIdx.x * 256 + t; i < E; i += NBKT * 256)
        atomicAdd(&h[row[i] >> 8], 1u);
    __syncthreads();
    for (int i = t; i < NBKT; i += 256)
        if (h[i]) atomicAdd(&bucketcnt[i], h[i]);
}

// ---------------- Pass B: exclusive scan of 391 bucket counts ----------------
__global__ __launch_bounds__(512) void bscan_kernel(const unsigned* __restrict__ bucketcnt,
                                                    unsigned* __restrict__ bucketbase,
                                                    unsigned* __restrict__ bucketcur) {
    __shared__ unsigned lds[512];
    int t = threadIdx.x;
    unsigned v = (t < NBKT) ? bucketcnt[t] : 0u;
    lds[t] = v;
    __syncthreads();
    for (int s = 1; s < 512; s <<= 1) {
        unsigned add = (t >= s) ? lds[t - s] : 0u;
        __syncthreads();
        lds[t] += add;
        __syncthreads();
    }
    if (t < NBKT) { unsigned b = lds[t] - v; bucketbase[t] = b; bucketcur[t] = b; }
}

// ---------------- Pass C: block-local multi-split partition ----------------
// 391 blocks x 4096 edges. LDS hist -> one global atomic per (block,bucket)
// -> packed 4B entries (rowlow<<24 | col), chunk-contiguous writes.
__global__ __launch_bounds__(256) void part_kernel(const int* __restrict__ row,
                                                   const int* __restrict__ col,
                                                   unsigned* __restrict__ bucketcur,
                                                   unsigned* __restrict__ entries, int E) {
    __shared__ unsigned h[NBKT];
    int t = threadIdx.x;
    for (int i = t; i < NBKT; i += 256) h[i] = 0;
    __syncthreads();
    int base_i = blockIdx.x * 4096;
    int r[16], c[16];
#pragma unroll
    for (int k = 0; k < 16; ++k) {
        int i = base_i + k * 256 + t;
        if (i < E) {
            r[k] = row[i]; c[k] = col[i];
            atomicAdd(&h[r[k] >> 8], 1u);
        } else r[k] = -1;
    }
    __syncthreads();
    for (int i = t; i < NBKT; i += 256) {
        unsigned cnt = h[i];
        if (cnt) h[i] = atomicAdd(&bucketcur[i], cnt);   // h becomes running cursor
    }
    __syncthreads();
#pragma unroll
    for (int k = 0; k < 16; ++k) {
        if (r[k] >= 0) {
            unsigned slot = atomicAdd(&h[r[k] >> 8], 1u);
            entries[slot] = ((unsigned)(r[k] & 255) << 24) | (unsigned)c[k];
        }
    }
}

// ---------------- degree + dinv from bucket entries (LDS counting) ----------------
__global__ __launch_bounds__(256) void degb_kernel(const unsigned* __restrict__ bucketbase,
                                                   const unsigned* __restrict__ bucketcnt,
                                                   const unsigned* __restrict__ entries,
                                                   float* __restrict__ dinv, int n) {
    __shared__ unsigned cnt[256];
    int t = threadIdx.x, b = blockIdx.x;
    cnt[t] = 0;
    __syncthreads();
    unsigned base = bucketbase[b], m = bucketcnt[b];
    for (unsigned j = t; j < m; j += 256) atomicAdd(&cnt[entries[base + j] >> 24], 1u);
    __syncthreads();
    int node = b * 256 + t;
    if (node < n) dinv[node] = cnt[t] ? rsqrtf((float)cnt[t]) : 0.f;
}

// ---------------- proj1: P0 = x@W1[0]; P1s = (x@W1[1]) * dinv ----------------
__global__ __launch_bounds__(256) void proj1_kernel(const float* __restrict__ x,
                                                    const float* __restrict__ W1,
                                                    const float* __restrict__ dinv,
                                                    float* __restrict__ P0,
                                                    float* __restrict__ P1s, int n) {
    __shared__ float lds[8 * 128];
    int base = blockIdx.x * 8;
    int t = threadIdx.x;
    {
        int rr = t >> 5, off = (t & 31) * 4;
        int nd = base + rr;
        float4 v = make_float4(0.f, 0.f, 0.f, 0.f);
        if (nd < n) v = *(const float4*)&x[(size_t)nd * 128 + off];
        *(float4*)&lds[rr * 128 + off] = v;
    }
    __syncthreads();
    int nl = t >> 5, j = t & 31;
    int node = base + nl;
    if (node >= n) return;
    const float* w  = W1 + (j < 16 ? 0 : 2048) + (j & 15);   // W1 is (2,128,16)
    const float* xr = lds + nl * 128;
    float acc = 0.f;
#pragma unroll
    for (int k = 0; k < 128; ++k) acc += xr[k] * w[k * 16];
    if (j < 16) P0[(size_t)node * 16 + j] = acc;
    else        P1s[(size_t)node * 16 + (j - 16)] = acc * dinv[node];
}

// ---------------- agg1: LDS-accumulated segment sum + relu epilogue ----------------
// one block per bucket; acc[256][16] in LDS; h = relu(P0 - dinv*acc + b1); HS = h*dinv
__global__ __launch_bounds__(1024) void agg1_kernel(const unsigned* __restrict__ bucketbase,
                                                    const unsigned* __restrict__ bucketcnt,
                                                    const unsigned* __restrict__ entries,
                                                    const float* __restrict__ dinv,
                                                    const float* __restrict__ P1s,
                                                    const float* __restrict__ b1,
                                                    float* __restrict__ H,     // in: P0, out: h (in-place)
                                                    float* __restrict__ HS, int n) {
    __shared__ float acc[256 * 16];
    int t = threadIdx.x, b = blockIdx.x;
    for (int i = t; i < 4096; i += 1024) acc[i] = 0.f;
    __syncthreads();
    unsigned base = bucketbase[b], m = bucketcnt[b];
    int g = t >> 4, f = t & 15;
    for (unsigned j = g; j < m; j += 64) {
        unsigned e = entries[base + j];
        int c = e & 0xFFFFFF, rl = e >> 24;
        atomicAdd(&acc[rl * 16 + f], P1s[(size_t)c * 16 + f]);
    }
    __syncthreads();
    int nl = t >> 2, fo = (t & 3) * 4;
    int node = b * 256 + nl;
    if (node < n) {
        float dr = dinv[node];
        float4 p  = *(float4*)&H[(size_t)node * 16 + fo];
        float4 a  = *(float4*)&acc[nl * 16 + fo];
        float4 bb = *(const float4*)&b1[fo];
        float4 v;
        v.x = fmaxf(p.x - dr * a.x + bb.x, 0.f);
        v.y = fmaxf(p.y - dr * a.y + bb.y, 0.f);
        v.z = fmaxf(p.z - dr * a.z + bb.z, 0.f);
        v.w = fmaxf(p.w - dr * a.w + bb.w, 0.f);
        *(float4*)&H[(size_t)node * 16 + fo] = v;
        float4 hs = make_float4(v.x * dr, v.y * dr, v.z * dr, v.w * dr);
        *(float4*)&HS[(size_t)node * 16 + fo] = hs;
    }
}

// ---------------- agg2: same gather on HS; ACC2 = -dinv * sum ----------------
__global__ __launch_bounds__(1024) void agg2_kernel(const unsigned* __restrict__ bucketbase,
                                                    const unsigned* __restrict__ bucketcnt,
                                                    const unsigned* __restrict__ entries,
                                                    const float* __restrict__ dinv,
                                                    const float* __restrict__ HS,
                                                    float* __restrict__ ACC2, int n) {
    __shared__ float acc[256 * 16];
    int t = threadIdx.x, b = blockIdx.x;
    for (int i = t; i < 4096; i += 1024) acc[i] = 0.f;
    __syncthreads();
    unsigned base = bucketbase[b], m = bucketcnt[b];
    int g = t >> 4, f = t & 15;
    for (unsigned j = g; j < m; j += 64) {
        unsigned e = entries[base + j];
        int c = e & 0xFFFFFF, rl = e >> 24;
        atomicAdd(&acc[rl * 16 + f], HS[(size_t)c * 16 + f]);
    }
    __syncthreads();
    int nl = t >> 2, fo = (t & 3) * 4;
    int node = b * 256 + nl;
    if (node < n) {
        float dr = dinv[node];
        float4 a = *(float4*)&acc[nl * 16 + fo];
        float4 v = make_float4(-dr * a.x, -dr * a.y, -dr * a.z, -dr * a.w);
        *(float4*)&ACC2[(size_t)node * 16 + fo] = v;
    }
}

// ---------------- out = log_softmax(h@W2[0] + ACC2@W2[1] + b2) ----------------
__global__ __launch_bounds__(256) void out_kernel(const float* __restrict__ H,
                                                  const float* __restrict__ ACC2,
                                                  const float* __restrict__ W2,
                                                  const float* __restrict__ b2,
                                                  float* __restrict__ out, int n) {
    int wave = threadIdx.x >> 6, lane = threadIdx.x & 63;
    int node = blockIdx.x * 4 + wave;
    if (node >= n) return;
    int f = lane & 15;
    float tval = ACC2[(size_t)node * 16 + f];
    float o0 = b2[lane], o1 = b2[lane + 64];
    const float* h = H + (size_t)node * 16;
#pragma unroll
    for (int k = 0; k < 16; ++k) {
        float tk = __shfl(tval, k);
        float hk = h[k];
        o0 += hk * W2[k * 128 + lane]      + tk * W2[2048 + k * 128 + lane];
        o1 += hk * W2[k * 128 + lane + 64] + tk * W2[2048 + k * 128 + lane + 64];
    }
    float mx = fmaxf(o0, o1);
#pragma unroll
    for (int s = 1; s < 64; s <<= 1) mx = fmaxf(mx, __shfl_xor(mx, s));
    float ssum = expf(o0 - mx) + expf(o1 - mx);
#pragma unroll
    for (int s = 1; s < 64; s <<= 1) ssum += __shfl_xor(ssum, s);
    float lse = mx + logf(ssum);
    out[(size_t)node * 128 + lane]      = o0 - lse;
    out[(size_t)node * 128 + lane + 64] = o1 - lse;
}

extern "C" void kernel_launch(void* const* d_in, const int* in_sizes, int n_in,
                              void* d_out, int out_size, void* d_ws, size_t ws_size,
                              hipStream_t stream) {
    const float* x  = (const float*)d_in[0];
    const int*   ei = (const int*)d_in[1];
    const float* W1 = (const float*)d_in[2];
    const float* b1 = (const float*)d_in[3];
    const float* W2 = (const float*)d_in[4];
    const float* b2 = (const float*)d_in[5];
    float* out = (float*)d_out;

    const int n = N_NODES, E = N_EDGES;
    const int* row = ei;
    const int* col = ei + E;

    // workspace layout (4B units); NPAD = 391*256 = 100096
    const size_t NPAD = 100096;
    unsigned* bucketcnt  = (unsigned*)d_ws;           // 512
    unsigned* bucketbase = bucketcnt + 512;           // 512
    unsigned* bucketcur  = bucketbase + 512;          // 512
    float*    dinv       = (float*)(bucketcur + 512); // NPAD
    unsigned* entries    = (unsigned*)(dinv + NPAD);  // E
    float*    P0         = (float*)(entries + E);     // NPAD*16  (becomes H in-place)
    float*    P1s        = P0 + NPAD * 16;            // NPAD*16  (becomes ACC2)
    float*    HS         = P1s + NPAD * 16;           // NPAD*16
    float*    ACC2       = P1s;                       // alias: P1s dead after agg1 gathers

    hipMemsetAsync(bucketcnt, 0, 512 * sizeof(unsigned), stream);

    bhist_kernel<<<NBKT, 256, 0, stream>>>(row, bucketcnt, E);
    bscan_kernel<<<1, 512, 0, stream>>>(bucketcnt, bucketbase, bucketcur);
    part_kernel<<<NBKT, 256, 0, stream>>>(row, col, bucketcur, entries, E);
    degb_kernel<<<NBKT, 256, 0, stream>>>(bucketbase, bucketcnt, entries, dinv, n);
    proj1_kernel<<<(n + 7) / 8, 256, 0, stream>>>(x, W1, dinv, P0, P1s, n);
    agg1_kernel<<<NBKT, 1024, 0, stream>>>(bucketbase, bucketcnt, entries, dinv, P1s, b1, P0, HS, n);
    agg2_kernel<<<NBKT, 1024, 0, stream>>>(bucketbase, bucketcnt, entries, dinv, HS, ACC2, n);
    out_kernel<<<(n + 3) / 4, 256, 0, stream>>>(P0, ACC2, W2, b2, out, n);
}

// Round 4
// 258.676 us; speedup vs baseline: 2.0992x; 2.0992x over previous
//
#include <hip/hip_runtime.h>

#define N_NODES 100000
#define N_EDGES 1600000
#define NBKT 391          // buckets of 256 rows (391*256 = 100096 >= N)
#define BCAP 6144         // per-bucket LDS staging capacity (mean 4096, sigma 64 -> +32 sigma)

// ---------------- Pass A: bucket histogram (LDS-reduced) ----------------
__global__ __launch_bounds__(256) void bhist_kernel(const int* __restrict__ row,
                                                    unsigned* __restrict__ bucketcnt, int E) {
    __shared__ unsigned h[NBKT];
    int t = threadIdx.x;
    for (int i = t; i < NBKT; i += 256) h[i] = 0;
    __syncthreads();
    for (int i = blockIdx.x * 256 + t; i < E; i += NBKT * 256)
        atomicAdd(&h[row[i] >> 8], 1u);
    __syncthreads();
    for (int i = t; i < NBKT; i += 256)
        if (h[i]) atomicAdd(&bucketcnt[i], h[i]);
}

// ---------------- Pass B: exclusive scan of 391 bucket counts ----------------
__global__ __launch_bounds__(512) void bscan_kernel(const unsigned* __restrict__ bucketcnt,
                                                    unsigned* __restrict__ bucketbase,
                                                    unsigned* __restrict__ bucketcur) {
    __shared__ unsigned lds[512];
    int t = threadIdx.x;
    unsigned v = (t < NBKT) ? bucketcnt[t] : 0u;
    lds[t] = v;
    __syncthreads();
    for (int s = 1; s < 512; s <<= 1) {
        unsigned add = (t >= s) ? lds[t - s] : 0u;
        __syncthreads();
        lds[t] += add;
        __syncthreads();
    }
    if (t < NBKT) { unsigned b = lds[t] - v; bucketbase[t] = b; bucketcur[t] = b; }
}

// ---------------- Pass C: block-local multi-split partition ----------------
// 391 blocks x 4096 edges; LDS hist -> 1 global atomic per (block,bucket);
// packed 4B entries (rowlow<<24 | col), chunk-contiguous writes.
__global__ __launch_bounds__(256) void part_kernel(const int* __restrict__ row,
                                                   const int* __restrict__ col,
                                                   unsigned* __restrict__ bucketcur,
                                                   unsigned* __restrict__ entries, int E) {
    __shared__ unsigned h[NBKT];
    int t = threadIdx.x;
    for (int i = t; i < NBKT; i += 256) h[i] = 0;
    __syncthreads();
    int base_i = blockIdx.x * 4096;
    int r[16], c[16];
#pragma unroll
    for (int k = 0; k < 16; ++k) {
        int i = base_i + k * 256 + t;
        if (i < E) {
            r[k] = row[i]; c[k] = col[i];
            atomicAdd(&h[r[k] >> 8], 1u);
        } else r[k] = -1;
    }
    __syncthreads();
    for (int i = t; i < NBKT; i += 256) {
        unsigned cnt = h[i];
        if (cnt) h[i] = atomicAdd(&bucketcur[i], cnt);   // h becomes running cursor
    }
    __syncthreads();
#pragma unroll
    for (int k = 0; k < 16; ++k) {
        if (r[k] >= 0) {
            unsigned slot = atomicAdd(&h[r[k] >> 8], 1u);
            entries[slot] = ((unsigned)(r[k] & 255) << 24) | (unsigned)c[k];
        }
    }
}

// ---------------- Pass D: per-bucket CSR finalize ----------------
// one block per bucket: LDS stage -> per-row hist -> scan -> in-place sort
// (entries becomes col-only, sorted by row); writes rs_deg (start,deg) + dinv.
__global__ __launch_bounds__(1024) void csr_kernel(const unsigned* __restrict__ bucketbase,
                                                   const unsigned* __restrict__ bucketcnt,
                                                   unsigned* __restrict__ entries,
                                                   uint2* __restrict__ rs_deg,
                                                   float* __restrict__ dinv, int n) {
    __shared__ unsigned se[BCAP];
    __shared__ unsigned cnt[256];
    __shared__ unsigned sc[256];
    __shared__ unsigned cur[256];
    int t = threadIdx.x, b = blockIdx.x;
    if (t < 256) cnt[t] = 0;
    __syncthreads();
    unsigned base = bucketbase[b], m = bucketcnt[b];
    for (unsigned j = t; j < m; j += 1024) {
        unsigned e = entries[base + j];
        if (j < BCAP) se[j] = e;
        atomicAdd(&cnt[e >> 24], 1u);
    }
    __syncthreads();
    if (t < 256) sc[t] = cnt[t];
    __syncthreads();
    for (int s = 1; s < 256; s <<= 1) {
        unsigned a = (t < 256 && t >= s) ? sc[t - s] : 0u;
        __syncthreads();
        if (t < 256) sc[t] += a;
        __syncthreads();
    }
    if (t < 256) {
        unsigned excl = sc[t] - cnt[t];
        cur[t] = excl;
        int node = b * 256 + t;
        if (node < n) {
            rs_deg[node] = make_uint2(base + excl, cnt[t]);
            dinv[node] = cnt[t] ? rsqrtf((float)cnt[t]) : 0.f;
        }
    }
    __syncthreads();
    for (unsigned j = t; j < m; j += 1024) {
        unsigned e = (j < BCAP) ? se[j] : entries[base + j];
        unsigned pos = atomicAdd(&cur[e >> 24], 1u);
        entries[base + pos] = e & 0xFFFFFF;
    }
}

// ---------------- proj1: P0 = x@W1[0]; P1s = (x@W1[1]) * dinv ----------------
__global__ __launch_bounds__(256) void proj1_kernel(const float* __restrict__ x,
                                                    const float* __restrict__ W1,
                                                    const float* __restrict__ dinv,
                                                    float* __restrict__ P0,
                                                    float* __restrict__ P1s, int n) {
    __shared__ float lds[8 * 128];
    int base = blockIdx.x * 8;
    int t = threadIdx.x;
    {
        int rr = t >> 5, off = (t & 31) * 4;
        int nd = base + rr;
        float4 v = make_float4(0.f, 0.f, 0.f, 0.f);
        if (nd < n) v = *(const float4*)&x[(size_t)nd * 128 + off];
        *(float4*)&lds[rr * 128 + off] = v;
    }
    __syncthreads();
    int nl = t >> 5, j = t & 31;
    int node = base + nl;
    if (node >= n) return;
    const float* w  = W1 + (j < 16 ? 0 : 2048) + (j & 15);   // W1 is (2,128,16)
    const float* xr = lds + nl * 128;
    float acc = 0.f;
#pragma unroll
    for (int k = 0; k < 128; ++k) acc += xr[k] * w[k * 16];
    if (j < 16) P0[(size_t)node * 16 + j] = acc;
    else        P1s[(size_t)node * 16 + (j - 16)] = acc * dinv[node];
}

// ---------------- agg1: wave-per-node segment sum + relu epilogue ----------------
// h = relu(P0 - dinv*sum(P1s[c]) + b1); HS = h*dinv. No atomics, 25K blocks.
__global__ __launch_bounds__(256) void agg1_kernel(const uint2* __restrict__ rs_deg,
                                                   const unsigned* __restrict__ ecol,
                                                   const float* __restrict__ dinv,
                                                   const float* __restrict__ P1s,
                                                   const float* __restrict__ b1,
                                                   float* __restrict__ H,   // in: P0, out: h
                                                   float* __restrict__ HS, int n) {
    int wave = threadIdx.x >> 6, lane = threadIdx.x & 63;
    int node = blockIdx.x * 4 + wave;
    if (node >= n) return;
    int f = lane & 15, slot = lane >> 4;
    uint2 rd = rs_deg[node];
    float s = 0.f;
    unsigned j = slot;
    for (; j + 4 < rd.y; j += 8) {      // 2-way MLP: two independent gathers in flight
        unsigned c0 = ecol[rd.x + j];
        unsigned c1 = ecol[rd.x + j + 4];
        s += P1s[(size_t)c0 * 16 + f] + P1s[(size_t)c1 * 16 + f];
    }
    if (j < rd.y) s += P1s[(size_t)ecol[rd.x + j] * 16 + f];
    s += __shfl_xor(s, 16);
    s += __shfl_xor(s, 32);
    if (slot == 0) {
        float dr = dinv[node];
        float v = H[(size_t)node * 16 + f] - dr * s + b1[f];
        v = fmaxf(v, 0.f);
        H[(size_t)node * 16 + f] = v;
        HS[(size_t)node * 16 + f] = v * dr;
    }
}

// ---------------- agg2 + out-proj + log_softmax, fully fused ----------------
__global__ __launch_bounds__(256) void agg2_out_kernel(const uint2* __restrict__ rs_deg,
                                                       const unsigned* __restrict__ ecol,
                                                       const float* __restrict__ dinv,
                                                       const float* __restrict__ HS,
                                                       const float* __restrict__ H,
                                                       const float* __restrict__ W2,
                                                       const float* __restrict__ b2,
                                                       float* __restrict__ out, int n) {
    int wave = threadIdx.x >> 6, lane = threadIdx.x & 63;
    int node = blockIdx.x * 4 + wave;
    if (node >= n) return;
    int f = lane & 15, slot = lane >> 4;
    uint2 rd = rs_deg[node];
    float s = 0.f;
    unsigned j = slot;
    for (; j + 4 < rd.y; j += 8) {
        unsigned c0 = ecol[rd.x + j];
        unsigned c1 = ecol[rd.x + j + 4];
        s += HS[(size_t)c0 * 16 + f] + HS[(size_t)c1 * 16 + f];
    }
    if (j < rd.y) s += HS[(size_t)ecol[rd.x + j] * 16 + f];
    s += __shfl_xor(s, 16);
    s += __shfl_xor(s, 32);
    s = -dinv[node] * s;               // Tx1' value for feature f, all lanes valid
    float o0 = b2[lane], o1 = b2[lane + 64];
    const float* h = H + (size_t)node * 16;
#pragma unroll
    for (int k = 0; k < 16; ++k) {
        float tk = __shfl(s, k);       // lane k holds f=k
        float hk = h[k];
        o0 += hk * W2[k * 128 + lane]      + tk * W2[2048 + k * 128 + lane];
        o1 += hk * W2[k * 128 + lane + 64] + tk * W2[2048 + k * 128 + lane + 64];
    }
    float mx = fmaxf(o0, o1);
#pragma unroll
    for (int st = 1; st < 64; st <<= 1) mx = fmaxf(mx, __shfl_xor(mx, st));
    float ssum = expf(o0 - mx) + expf(o1 - mx);
#pragma unroll
    for (int st = 1; st < 64; st <<= 1) ssum += __shfl_xor(ssum, st);
    float lse = mx + logf(ssum);
    out[(size_t)node * 128 + lane]      = o0 - lse;
    out[(size_t)node * 128 + lane + 64] = o1 - lse;
}

extern "C" void kernel_launch(void* const* d_in, const int* in_sizes, int n_in,
                              void* d_out, int out_size, void* d_ws, size_t ws_size,
                              hipStream_t stream) {
    const float* x  = (const float*)d_in[0];
    const int*   ei = (const int*)d_in[1];
    const float* W1 = (const float*)d_in[2];
    const float* b1 = (const float*)d_in[3];
    const float* W2 = (const float*)d_in[4];
    const float* b2 = (const float*)d_in[5];
    float* out = (float*)d_out;

    const int n = N_NODES, E = N_EDGES;
    const int* row = ei;
    const int* col = ei + E;

    // workspace layout (4B units); NPAD = 391*256 = 100096
    const size_t NPAD = 100096;
    unsigned* bucketcnt  = (unsigned*)d_ws;              // 512
    unsigned* bucketbase = bucketcnt + 512;              // 512
    unsigned* bucketcur  = bucketbase + 512;             // 512  (offset 6KB -> 8B aligned next)
    uint2*    rs_deg     = (uint2*)(bucketcur + 512);    // NPAD uint2
    float*    dinv       = (float*)(rs_deg + NPAD);      // NPAD
    unsigned* entries    = (unsigned*)(dinv + NPAD);     // E (packed, then col-only CSR)
    float*    P0         = (float*)(entries + E);        // NPAD*16 (becomes H in-place)
    float*    P1s        = P0 + NPAD * 16;               // NPAD*16
    float*    HS         = P1s + NPAD * 16;              // NPAD*16

    hipMemsetAsync(bucketcnt, 0, 512 * sizeof(unsigned), stream);

    bhist_kernel<<<NBKT, 256, 0, stream>>>(row, bucketcnt, E);
    bscan_kernel<<<1, 512, 0, stream>>>(bucketcnt, bucketbase, bucketcur);
    part_kernel<<<NBKT, 256, 0, stream>>>(row, col, bucketcur, entries, E);
    csr_kernel<<<NBKT, 1024, 0, stream>>>(bucketbase, bucketcnt, entries, rs_deg, dinv, n);
    proj1_kernel<<<(n + 7) / 8, 256, 0, stream>>>(x, W1, dinv, P0, P1s, n);
    agg1_kernel<<<(n + 3) / 4, 256, 0, stream>>>(rs_deg, entries, dinv, P1s, b1, P0, HS, n);
    agg2_out_kernel<<<(n + 3) / 4, 256, 0, stream>>>(rs_deg, entries, dinv, HS, P0, W2, b2, out, n);
}

// Round 5
// 215.008 us; speedup vs baseline: 2.5255x; 1.2031x over previous
//
#include <hip/hip_runtime.h>

#define N_NODES 100000
#define N_EDGES 1600000
#define NBKT 391          // buckets of 256 rows (391*256 = 100096 >= N)
#define BCAP 6144         // per-bucket LDS staging capacity (mean 4096, sigma ~64)

// ---------------- Pass A: bucket histogram (LDS-reduced) ----------------
__global__ __launch_bounds__(256) void bhist_kernel(const int* __restrict__ row,
                                                    unsigned* __restrict__ bucketcnt, int E) {
    __shared__ unsigned h[NBKT];
    int t = threadIdx.x;
    for (int i = t; i < NBKT; i += 256) h[i] = 0;
    __syncthreads();
    for (int i = blockIdx.x * 256 + t; i < E; i += NBKT * 256)
        atomicAdd(&h[row[i] >> 8], 1u);
    __syncthreads();
    for (int i = t; i < NBKT; i += 256)
        if (h[i]) atomicAdd(&bucketcnt[i], h[i]);
}

// ---------------- Pass B: exclusive scan of 391 bucket counts ----------------
__global__ __launch_bounds__(512) void bscan_kernel(const unsigned* __restrict__ bucketcnt,
                                                    unsigned* __restrict__ bucketbase,
                                                    unsigned* __restrict__ bucketcur) {
    __shared__ unsigned lds[512];
    int t = threadIdx.x;
    unsigned v = (t < NBKT) ? bucketcnt[t] : 0u;
    lds[t] = v;
    __syncthreads();
    for (int s = 1; s < 512; s <<= 1) {
        unsigned add = (t >= s) ? lds[t - s] : 0u;
        __syncthreads();
        lds[t] += add;
        __syncthreads();
    }
    if (t < NBKT) { unsigned b = lds[t] - v; bucketbase[t] = b; bucketcur[t] = b; }
}

// ---------------- Pass C: block-local multi-split partition ----------------
__global__ __launch_bounds__(256) void part_kernel(const int* __restrict__ row,
                                                   const int* __restrict__ col,
                                                   unsigned* __restrict__ bucketcur,
                                                   unsigned* __restrict__ entries, int E) {
    __shared__ unsigned h[NBKT];
    int t = threadIdx.x;
    for (int i = t; i < NBKT; i += 256) h[i] = 0;
    __syncthreads();
    int base_i = blockIdx.x * 4096;
    int r[16], c[16];
#pragma unroll
    for (int k = 0; k < 16; ++k) {
        int i = base_i + k * 256 + t;
        if (i < E) {
            r[k] = row[i]; c[k] = col[i];
            atomicAdd(&h[r[k] >> 8], 1u);
        } else r[k] = -1;
    }
    __syncthreads();
    for (int i = t; i < NBKT; i += 256) {
        unsigned cnt = h[i];
        if (cnt) h[i] = atomicAdd(&bucketcur[i], cnt);   // h becomes running cursor
    }
    __syncthreads();
#pragma unroll
    for (int k = 0; k < 16; ++k) {
        if (r[k] >= 0) {
            unsigned slot = atomicAdd(&h[r[k] >> 8], 1u);
            entries[slot] = ((unsigned)(r[k] & 255) << 24) | (unsigned)c[k];
        }
    }
}

// ---------------- Pass D: per-bucket CSR finalize ----------------
__global__ __launch_bounds__(1024) void csr_kernel(const unsigned* __restrict__ bucketbase,
                                                   const unsigned* __restrict__ bucketcnt,
                                                   unsigned* __restrict__ entries,
                                                   uint2* __restrict__ rs_deg,
                                                   float* __restrict__ dinv, int n) {
    __shared__ unsigned se[BCAP];
    __shared__ unsigned cnt[256];
    __shared__ unsigned sc[256];
    __shared__ unsigned cur[256];
    int t = threadIdx.x, b = blockIdx.x;
    if (t < 256) cnt[t] = 0;
    __syncthreads();
    unsigned base = bucketbase[b], m = bucketcnt[b];
    for (unsigned j = t; j < m; j += 1024) {
        unsigned e = entries[base + j];
        if (j < BCAP) se[j] = e;
        atomicAdd(&cnt[e >> 24], 1u);
    }
    __syncthreads();
    if (t < 256) sc[t] = cnt[t];
    __syncthreads();
    for (int s = 1; s < 256; s <<= 1) {
        unsigned a = (t < 256 && t >= s) ? sc[t - s] : 0u;
        __syncthreads();
        if (t < 256) sc[t] += a;
        __syncthreads();
    }
    if (t < 256) {
        unsigned excl = sc[t] - cnt[t];
        cur[t] = excl;
        int node = b * 256 + t;
        if (node < n) {
            rs_deg[node] = make_uint2(base + excl, cnt[t]);
            dinv[node] = cnt[t] ? rsqrtf((float)cnt[t]) : 0.f;
        }
    }
    __syncthreads();
    for (unsigned j = t; j < m; j += 1024) {
        unsigned e = (j < BCAP) ? se[j] : entries[base + j];
        unsigned pos = atomicAdd(&cur[e >> 24], 1u);
        entries[base + pos] = e & 0xFFFFFF;
    }
}

// ---------------- proj1 v2: register-blocked; P0 = x@W1[0], P1s = (x@W1[1])*dinv ----
// 64 nodes/block; x-tile [64][132] + transposed W1 [32][132] in LDS.
// Thread (nl = t>>2, q = t&3) computes outputs j = q*8..q*8+7 for node nl.
__global__ __launch_bounds__(256) void proj1_kernel(const float* __restrict__ x,
                                                    const float* __restrict__ W1,
                                                    const float* __restrict__ dinv,
                                                    float* __restrict__ P0,
                                                    float* __restrict__ P1s, int n) {
    __shared__ float xs[64 * 132];
    __shared__ float wt[32 * 132];
    int t = threadIdx.x;
    int base = blockIdx.x * 64;
    // stage W1 transposed: wt row r = (j&7)*4 + (j>>3)  (j = combined output 0..31)
    for (int idx = t; idx < 32 * 128; idx += 256) {
        int j = idx >> 7, k = idx & 127;
        int r = (j & 7) * 4 + (j >> 3);
        wt[r * 132 + k] = W1[((j >> 4) ? 2048 : 0) + k * 16 + (j & 15)];
    }
    // stage x-tile, coalesced float4
    for (int idx = t; idx < 2048; idx += 256) {
        int row = idx >> 5, c4 = idx & 31;
        int node = base + row;
        float4 v = make_float4(0.f, 0.f, 0.f, 0.f);
        if (node < n) v = *(const float4*)&x[(size_t)node * 128 + c4 * 4];
        *(float4*)&xs[row * 132 + c4 * 4] = v;
    }
    __syncthreads();
    int nl = t >> 2, q = t & 3;
    int node = base + nl;
    float acc[8] = {0.f, 0.f, 0.f, 0.f, 0.f, 0.f, 0.f, 0.f};
    const float* xr = xs + nl * 132;
    const float* wb = wt + q * 132;
#pragma unroll 4
    for (int kb = 0; kb < 32; ++kb) {
        float4 xv = *(const float4*)&xr[kb * 4];
#pragma unroll
        for (int jj = 0; jj < 8; ++jj) {
            float4 wv = *(const float4*)&wb[jj * 4 * 132 + kb * 4];
            acc[jj] += xv.x * wv.x + xv.y * wv.y + xv.z * wv.z + xv.w * wv.w;
        }
    }
    if (node >= n) return;
    if (q < 2) {
        *(float4*)&P0[(size_t)node * 16 + q * 8]     = make_float4(acc[0], acc[1], acc[2], acc[3]);
        *(float4*)&P0[(size_t)node * 16 + q * 8 + 4] = make_float4(acc[4], acc[5], acc[6], acc[7]);
    } else {
        float dr = dinv[node];
        int o = (q - 2) * 8;
        *(float4*)&P1s[(size_t)node * 16 + o]     = make_float4(acc[0]*dr, acc[1]*dr, acc[2]*dr, acc[3]*dr);
        *(float4*)&P1s[(size_t)node * 16 + o + 4] = make_float4(acc[4]*dr, acc[5]*dr, acc[6]*dr, acc[7]*dr);
    }
}

// ---------------- agg1: wave-per-node segment sum + relu epilogue ----------------
// h = relu(P0 - dinv*sum(P1s[c]) + b1); HS = h*dinv. 4-deep unrolled gathers.
__global__ __launch_bounds__(256) void agg1_kernel(const uint2* __restrict__ rs_deg,
                                                   const unsigned* __restrict__ ecol,
                                                   const float* __restrict__ dinv,
                                                   const float* __restrict__ P1s,
                                                   const float* __restrict__ b1,
                                                   float* __restrict__ H,   // in: P0, out: h
                                                   float* __restrict__ HS, int n) {
    int wave = threadIdx.x >> 6, lane = threadIdx.x & 63;
    int node = blockIdx.x * 4 + wave;
    if (node >= n) return;
    int f = lane & 15, slot = lane >> 4;
    uint2 rd = rs_deg[node];
    float s = 0.f;
    unsigned j = slot, d = rd.y;
    for (; j + 12 < d; j += 16) {
        unsigned c0 = ecol[rd.x + j];
        unsigned c1 = ecol[rd.x + j + 4];
        unsigned c2 = ecol[rd.x + j + 8];
        unsigned c3 = ecol[rd.x + j + 12];
        s += P1s[(size_t)c0 * 16 + f] + P1s[(size_t)c1 * 16 + f]
           + P1s[(size_t)c2 * 16 + f] + P1s[(size_t)c3 * 16 + f];
    }
    for (; j < d; j += 4) s += P1s[(size_t)ecol[rd.x + j] * 16 + f];
    s += __shfl_xor(s, 16);
    s += __shfl_xor(s, 32);
    if (slot == 0) {
        float dr = dinv[node];
        float v = H[(size_t)node * 16 + f] - dr * s + b1[f];
        v = fmaxf(v, 0.f);
        H[(size_t)node * 16 + f] = v;
        HS[(size_t)node * 16 + f] = v * dr;
    }
}

// ---------------- agg2 + out-proj + log_softmax, fully fused ----------------
__global__ __launch_bounds__(256) void agg2_out_kernel(const uint2* __restrict__ rs_deg,
                                                       const unsigned* __restrict__ ecol,
                                                       const float* __restrict__ dinv,
                                                       const float* __restrict__ HS,
                                                       const float* __restrict__ H,
                                                       const float* __restrict__ W2,
                                                       const float* __restrict__ b2,
                                                       float* __restrict__ out, int n) {
    int wave = threadIdx.x >> 6, lane = threadIdx.x & 63;
    int node = blockIdx.x * 4 + wave;
    if (node >= n) return;
    int f = lane & 15, slot = lane >> 4;
    uint2 rd = rs_deg[node];
    float s = 0.f;
    unsigned j = slot, d = rd.y;
    for (; j + 12 < d; j += 16) {
        unsigned c0 = ecol[rd.x + j];
        unsigned c1 = ecol[rd.x + j + 4];
        unsigned c2 = ecol[rd.x + j + 8];
        unsigned c3 = ecol[rd.x + j + 12];
        s += HS[(size_t)c0 * 16 + f] + HS[(size_t)c1 * 16 + f]
           + HS[(size_t)c2 * 16 + f] + HS[(size_t)c3 * 16 + f];
    }
    for (; j < d; j += 4) s += HS[(size_t)ecol[rd.x + j] * 16 + f];
    s += __shfl_xor(s, 16);
    s += __shfl_xor(s, 32);
    s = -dinv[node] * s;               // Tx1' value for feature f, all lanes valid
    float o0 = b2[lane], o1 = b2[lane + 64];
    const float* h = H + (size_t)node * 16;
#pragma unroll
    for (int k = 0; k < 16; ++k) {
        float tk = __shfl(s, k);       // lane k holds f=k
        float hk = h[k];
        o0 += hk * W2[k * 128 + lane]      + tk * W2[2048 + k * 128 + lane];
        o1 += hk * W2[k * 128 + lane + 64] + tk * W2[2048 + k * 128 + lane + 64];
    }
    float mx = fmaxf(o0, o1);
#pragma unroll
    for (int st = 1; st < 64; st <<= 1) mx = fmaxf(mx, __shfl_xor(mx, st));
    float ssum = expf(o0 - mx) + expf(o1 - mx);
#pragma unroll
    for (int st = 1; st < 64; st <<= 1) ssum += __shfl_xor(ssum, st);
    float lse = mx + logf(ssum);
    out[(size_t)node * 128 + lane]      = o0 - lse;
    out[(size_t)node * 128 + lane + 64] = o1 - lse;
}

extern "C" void kernel_launch(void* const* d_in, const int* in_sizes, int n_in,
                              void* d_out, int out_size, void* d_ws, size_t ws_size,
                              hipStream_t stream) {
    const float* x  = (const float*)d_in[0];
    const int*   ei = (const int*)d_in[1];
    const float* W1 = (const float*)d_in[2];
    const float* b1 = (const float*)d_in[3];
    const float* W2 = (const float*)d_in[4];
    const float* b2 = (const float*)d_in[5];
    float* out = (float*)d_out;

    const int n = N_NODES, E = N_EDGES;
    const int* row = ei;
    const int* col = ei + E;

    // workspace layout (4B units); NPAD = 391*256 = 100096
    const size_t NPAD = 100096;
    unsigned* bucketcnt  = (unsigned*)d_ws;              // 512
    unsigned* bucketbase = bucketcnt + 512;              // 512
    unsigned* bucketcur  = bucketbase + 512;             // 512
    uint2*    rs_deg     = (uint2*)(bucketcur + 512);    // NPAD uint2
    float*    dinv       = (float*)(rs_deg + NPAD);      // NPAD
    unsigned* entries    = (unsigned*)(dinv + NPAD);     // E (packed, then col-only CSR)
    float*    P0         = (float*)(entries + E);        // NPAD*16 (becomes H in-place)
    float*    P1s        = P0 + NPAD * 16;               // NPAD*16
    float*    HS         = P1s + NPAD * 16;              // NPAD*16

    hipMemsetAsync(bucketcnt, 0, 512 * sizeof(unsigned), stream);

    bhist_kernel<<<NBKT, 256, 0, stream>>>(row, bucketcnt, E);
    bscan_kernel<<<1, 512, 0, stream>>>(bucketcnt, bucketbase, bucketcur);
    part_kernel<<<NBKT, 256, 0, stream>>>(row, col, bucketcur, entries, E);
    csr_kernel<<<NBKT, 1024, 0, stream>>>(bucketbase, bucketcnt, entries, rs_deg, dinv, n);
    proj1_kernel<<<(n + 63) / 64, 256, 0, stream>>>(x, W1, dinv, P0, P1s, n);
    agg1_kernel<<<(n + 3) / 4, 256, 0, stream>>>(rs_deg, entries, dinv, P1s, b1, P0, HS, n);
    agg2_out_kernel<<<(n + 3) / 4, 256, 0, stream>>>(rs_deg, entries, dinv, HS, P0, W2, b2, out, n);
}